// Round 7
// baseline (716.683 us; speedup 1.0000x reference)
//
#include <hip/hip_runtime.h>
#include <math.h>

#define ZR 128
#define NR 512

// cells: 4(z) x 32(x) x 32(y) voxels -> 32*16*16 = 8192 cells
#define NCX 16
#define NCY 16
#define NCELL 8192
#define CAP 512                 // per-cell record capacity (mean 244, Poisson sigma ~16)
#define SLZ 5
#define SLX 33
#define SLY 33
#define SVOL (SLZ * SLX * SLY)  // 5445 floats = 21780 B LDS

typedef unsigned int u32x4 __attribute__((ext_vector_type(4)));

// nontemporal stream so zcheck doesn't evict cached albedo
__device__ __forceinline__ void zcheck_range(
    const u32x4* __restrict__ normal4, long long lo, long long hi,
    long long rank, long long nthreads, unsigned int* __restrict__ flag)
{
    unsigned int acc = 0;
    long long i = lo + rank * 256 + threadIdx.x;
    for (; i + nthreads < hi; i += 2 * nthreads) {
        u32x4 v0 = __builtin_nontemporal_load(&normal4[i]);
        u32x4 v1 = __builtin_nontemporal_load(&normal4[i + nthreads]);
        acc |= v0.x | v0.y | v0.z | v0.w | v1.x | v1.y | v1.z | v1.w;
    }
    if (i < hi) {
        u32x4 v = __builtin_nontemporal_load(&normal4[i]);
        acc |= v.x | v.y | v.z | v.w;
    }
    if (__ballot(acc != 0) && ((threadIdx.x & 63) == 0))
        atomicOr(flag, 1u);
}

// ---------------- kernel A: point->cell scatter + full zcheck + out_n fill ----------------
// grid = SB (scatter) + ZB (zcheck) + FB (out_n fill)
__global__ __launch_bounds__(256) void scatter_zcheck_fill_kernel(
    const float* __restrict__ coords,
    const u32x4* __restrict__ normal4,
    const unsigned int* __restrict__ normal_tail, int tail_cnt,
    unsigned int* __restrict__ flag,
    unsigned int* __restrict__ cnt,        // [NCELL]
    unsigned int* __restrict__ ovf_cnt,
    float4* __restrict__ recs,             // [NCELL * CAP]
    float4* __restrict__ ovf,              // [M]
    float* __restrict__ out_n,
    int M, long long n4, int SB, int ZB, int FB)
{
    unsigned int b = blockIdx.x;

    if (b < (unsigned)SB) {
        // scatter role: 8 pts/thread
        int base = (int)b * 2048;
#pragma unroll
        for (int k = 0; k < 8; k++) {
            int i = base + k * 256 + (int)threadIdx.x;
            if (i >= M) break;
            size_t o = 3 * (size_t)i;
            float cz = coords[o], cx = coords[o + 1], cy = coords[o + 2];
            int z0 = min(max((int)floorf(cz), 0), ZR - 1);
            int x0 = min(max((int)floorf(cx), 0), NR - 1);
            int y0 = min(max((int)floorf(cy), 0), NR - 1);
            int cell = ((z0 >> 2) * NCX + (x0 >> 5)) * NCY + (y0 >> 5);
            unsigned int slot = atomicAdd(&cnt[cell], 1u);
            float4 r;
            r.x = cz; r.y = cx; r.z = cy; r.w = __uint_as_float((unsigned int)i);
            if (slot < CAP) {
                recs[(size_t)cell * CAP + slot] = r;
            } else {
                unsigned int os = atomicAdd(ovf_cnt, 1u);
                ovf[os] = r;
            }
        }
        return;
    }
    b -= (unsigned)SB;

    if (b < (unsigned)ZB) {
        if (b == 0 && threadIdx.x < (unsigned)tail_cnt) {
            if (normal_tail[threadIdx.x]) atomicOr(flag, 1u);
        }
        zcheck_range(normal4, 0, n4, (long long)b, (long long)ZB * 256, flag);
        return;
    }
    b -= (unsigned)ZB;

    // out_n constant-pattern fill (valid iff flag==0; else overwritten by normal_full)
    long long total = 3LL * M;
    if ((M & 3) == 0) {
        long long f4 = (long long)b * 256 + threadIdx.x;
        long long nf4 = total >> 2;
        if (f4 < nf4) {
            const unsigned int B = 0xBF800000u;   // -1.0f
            int rmod = (int)(f4 % 3);
            u32x4 v;
            if (rmod == 0)      v = (u32x4){B, 0u, 0u, B};
            else if (rmod == 1) v = (u32x4){0u, 0u, B, 0u};
            else                v = (u32x4){0u, B, 0u, 0u};
            __builtin_nontemporal_store(v, &((u32x4*)out_n)[f4]);
        }
    } else {
        long long stride = (long long)FB * 256;
        for (long long qq = (long long)b * 256 + threadIdx.x; qq < total; qq += stride)
            out_n[qq] = ((qq % 3) == 0) ? -1.0f : 0.0f;
    }
}

// ---------------- kernel B: per-cell LDS-staged interpolation (fp32 exact taps) ----------------
// grid = NCELL, one block per cell. Stages 5x33x33 fp32 region (clamped halo), then
// serves all the cell's points' 8 taps from LDS.
__global__ __launch_bounds__(256) void interp_cell_kernel(
    const float* __restrict__ albedo,
    const unsigned int* __restrict__ cnt,
    const float4* __restrict__ recs,
    float* __restrict__ out_a)
{
    __shared__ float s[SVOL];

    int c = blockIdx.x;
    int zc = c >> 8;             // / (NCX*NCY)
    int xc = (c >> 4) & 15;
    int yc = c & 15;
    int Z = zc << 2, X = xc << 5, Y = yc << 5;

    for (int i = threadIdx.x; i < SVOL; i += 256) {
        int lz = i / (SLX * SLY);
        int rem = i - lz * (SLX * SLY);
        int lx = rem / SLY;
        int ly = rem - lx * SLY;
        int gz = min(Z + lz, ZR - 1);
        int gx = min(X + lx, NR - 1);
        int gy = min(Y + ly, NR - 1);
        s[i] = albedo[((size_t)gz * NR + gx) * NR + gy];
    }
    __syncthreads();

    int np = min((int)cnt[c], CAP);
    const float4* rbase = recs + (size_t)c * CAP;

    for (int p = threadIdx.x; p < np; p += 256) {
        float4 r = rbase[p];
        float cz = r.x, cx = r.y, cy = r.z;
        unsigned int idx = __float_as_uint(r.w);

        float fz0 = floorf(cz), fx0 = floorf(cx), fy0 = floorf(cy);
        float fz = cz - fz0, fx = cx - fx0, fy = cy - fy0;

        int z0 = min(max((int)fz0, 0), ZR - 1);
        int x0 = min(max((int)fx0, 0), NR - 1);
        int y0 = min(max((int)fy0, 0), NR - 1);

        float gz = 1.0f - fz, gx = 1.0f - fx, gy = 1.0f - fy;
        float w000 = gz * gx * gy, w001 = gz * gx * fy;
        float w010 = gz * fx * gy, w011 = gz * fx * fy;
        float w100 = fz * gx * gy, w101 = fz * gx * fy;
        float w110 = fz * fx * gy, w111 = fz * fx * fy;

        int lz0 = z0 - Z, lx0 = x0 - X, ly0 = y0 - Y;
        int b00 = lz0 * (SLX * SLY) + lx0 * SLY + ly0;      // z0,x0,y0
        int b01 = b00 + SLY;                                 // z0,x1
        int b10 = b00 + (SLX * SLY);                         // z1,x0
        int b11 = b10 + SLY;                                 // z1,x1

        float a =
            s[b00] * w000 + s[b00 + 1] * w001 +
            s[b01] * w010 + s[b01 + 1] * w011 +
            s[b10] * w100 + s[b10 + 1] * w101 +
            s[b11] * w110 + s[b11 + 1] * w111;

        a = (a > 0.0f) ? a : expm1f(a);
        out_a[idx] = a;
    }
}

// ---------------- kernel C: overflow cleanup (direct fp32 gather; rare/empty) ----------------
__global__ __launch_bounds__(256) void overflow_kernel(
    const float4* __restrict__ ovf,
    const unsigned int* __restrict__ ovf_cnt,
    const float* __restrict__ albedo,
    float* __restrict__ out_a,
    int M)
{
    int n = (int)*ovf_cnt;
    if (n <= 0) return;
    if (n > M) n = M;
    int stride = gridDim.x * 256;
    for (int p = blockIdx.x * 256 + threadIdx.x; p < n; p += stride) {
        float4 r = ovf[p];
        float cz = r.x, cx = r.y, cy = r.z;
        unsigned int idx = __float_as_uint(r.w);

        float fz0 = floorf(cz), fx0 = floorf(cx), fy0 = floorf(cy);
        float fz = cz - fz0, fx = cx - fx0, fy = cy - fy0;

        int z0 = min(max((int)fz0, 0), ZR - 1);
        int x0 = min(max((int)fx0, 0), NR - 1);
        int y0 = min(max((int)fy0, 0), NR - 1);
        int z1 = min(z0 + 1, ZR - 1);
        int x1 = min(x0 + 1, NR - 1);
        int y1 = min(y0 + 1, NR - 1);

        float gz = 1.0f - fz, gx = 1.0f - fx, gy = 1.0f - fy;
        float w000 = gz * gx * gy, w001 = gz * gx * fy;
        float w010 = gz * fx * gy, w011 = gz * fx * fy;
        float w100 = fz * gx * gy, w101 = fz * gx * fy;
        float w110 = fz * fx * gy, w111 = fz * fx * fy;

        size_t b00 = ((size_t)z0 * NR + x0) * NR;
        size_t b01 = ((size_t)z0 * NR + x1) * NR;
        size_t b10 = ((size_t)z1 * NR + x0) * NR;
        size_t b11 = ((size_t)z1 * NR + x1) * NR;

        float a =
            albedo[b00 + y0] * w000 + albedo[b00 + y1] * w001 +
            albedo[b01 + y0] * w010 + albedo[b01 + y1] * w011 +
            albedo[b10 + y0] * w100 + albedo[b10 + y1] * w101 +
            albedo[b11 + y0] * w110 + albedo[b11 + y1] * w111;

        a = (a > 0.0f) ? a : expm1f(a);
        out_a[idx] = a;
    }
}

// ---------------- slow path: recompute out_n when `normal` has content ----------------
__global__ __launch_bounds__(256) void normal_full_kernel(
    const float* __restrict__ coords,
    const float* __restrict__ normal,
    const unsigned int* __restrict__ flag,
    float* __restrict__ out_n,
    int M)
{
    if (*flag == 0) return;

    int stride = gridDim.x * 256;
    for (int i = blockIdx.x * 256 + threadIdx.x; i < M; i += stride) {
        float cz = coords[3 * i + 0];
        float cx = coords[3 * i + 1];
        float cy = coords[3 * i + 2];

        float fz0 = floorf(cz), fx0 = floorf(cx), fy0 = floorf(cy);
        float fz = cz - fz0, fx = cx - fx0, fy = cy - fy0;

        int z0 = min(max((int)fz0, 0), ZR - 1);
        int x0 = min(max((int)fx0, 0), NR - 1);
        int y0 = min(max((int)fy0, 0), NR - 1);
        int z1 = min(z0 + 1, ZR - 1);
        int x1 = min(x0 + 1, NR - 1);
        int y1 = min(y0 + 1, NR - 1);

        float gz = 1.0f - fz, gx = 1.0f - fx, gy = 1.0f - fy;

        float w000 = gz * gx * gy, w001 = gz * gx * fy;
        float w010 = gz * fx * gy, w011 = gz * fx * fy;
        float w100 = fz * gx * gy, w101 = fz * gx * fy;
        float w110 = fz * fx * gy, w111 = fz * fx * fy;

        size_t b00 = ((size_t)z0 * NR + x0) * NR;
        size_t b01 = ((size_t)z0 * NR + x1) * NR;
        size_t b10 = ((size_t)z1 * NR + x0) * NR;
        size_t b11 = ((size_t)z1 * NR + x1) * NR;

        float n0 = 0.0f, n1 = 0.0f, n2 = 0.0f;
#define ACC(base, yy, w)                                           \
        {                                                          \
            const float* qp = normal + ((base) + (size_t)(yy)) * 3;\
            n0 += qp[0] * (w);                                     \
            n1 += qp[1] * (w);                                     \
            n2 += qp[2] * (w);                                     \
        }
        ACC(b00, y0, w000); ACC(b00, y1, w001);
        ACC(b01, y0, w010); ACC(b01, y1, w011);
        ACC(b10, y0, w100); ACC(b10, y1, w101);
        ACC(b11, y0, w110); ACC(b11, y1, w111);
#undef ACC

        n0 = tanhf(n0) - 1.0f;
        n1 = tanhf(n1);
        n2 = tanhf(n2);

        float nrm = sqrtf(n0 * n0 + n1 * n1 + n2 * n2);
        nrm = fmaxf(nrm, 1e-12f);
        float inv = 1.0f / nrm;

        out_n[3 * i + 0] = n0 * inv;
        out_n[3 * i + 1] = n1 * inv;
        out_n[3 * i + 2] = n2 * inv;
    }
}

// ---------------- fallback: fully general direct kernel (ws too small) ----------------
__global__ __launch_bounds__(256) void devox_direct(
    const float* __restrict__ coords,
    const float* __restrict__ albedo,
    const float* __restrict__ normal,
    float* __restrict__ out_a,
    float* __restrict__ out_n,
    int M)
{
    int i = blockIdx.x * 256 + threadIdx.x;
    if (i >= M) return;

    float cz = coords[3 * i + 0];
    float cx = coords[3 * i + 1];
    float cy = coords[3 * i + 2];

    float fz0 = floorf(cz), fx0 = floorf(cx), fy0 = floorf(cy);
    float fz = cz - fz0, fx = cx - fx0, fy = cy - fy0;

    int z0 = min(max((int)fz0, 0), ZR - 1);
    int x0 = min(max((int)fx0, 0), NR - 1);
    int y0 = min(max((int)fy0, 0), NR - 1);
    int z1 = min(z0 + 1, ZR - 1);
    int x1 = min(x0 + 1, NR - 1);
    int y1 = min(y0 + 1, NR - 1);

    float gz = 1.0f - fz, gx = 1.0f - fx, gy = 1.0f - fy;
    float w000 = gz * gx * gy, w001 = gz * gx * fy;
    float w010 = gz * fx * gy, w011 = gz * fx * fy;
    float w100 = fz * gx * gy, w101 = fz * gx * fy;
    float w110 = fz * fx * gy, w111 = fz * fx * fy;

    size_t b00 = ((size_t)z0 * NR + x0) * NR;
    size_t b01 = ((size_t)z0 * NR + x1) * NR;
    size_t b10 = ((size_t)z1 * NR + x0) * NR;
    size_t b11 = ((size_t)z1 * NR + x1) * NR;

    float a =
        albedo[b00 + y0] * w000 + albedo[b00 + y1] * w001 +
        albedo[b01 + y0] * w010 + albedo[b01 + y1] * w011 +
        albedo[b10 + y0] * w100 + albedo[b10 + y1] * w101 +
        albedo[b11 + y0] * w110 + albedo[b11 + y1] * w111;

    float n0 = 0.0f, n1 = 0.0f, n2 = 0.0f;
#define ACC(base, yy, w)                                           \
    {                                                              \
        const float* qp = normal + ((base) + (size_t)(yy)) * 3;    \
        n0 += qp[0] * (w);                                         \
        n1 += qp[1] * (w);                                         \
        n2 += qp[2] * (w);                                         \
    }
    ACC(b00, y0, w000); ACC(b00, y1, w001);
    ACC(b01, y0, w010); ACC(b01, y1, w011);
    ACC(b10, y0, w100); ACC(b10, y1, w101);
    ACC(b11, y0, w110); ACC(b11, y1, w111);
#undef ACC

    a = (a > 0.0f) ? a : expm1f(a);
    n0 = tanhf(n0) - 1.0f;
    n1 = tanhf(n1);
    n2 = tanhf(n2);
    float nrm = sqrtf(n0 * n0 + n1 * n1 + n2 * n2);
    nrm = fmaxf(nrm, 1e-12f);
    float inv = 1.0f / nrm;

    out_a[i] = a;
    out_n[3 * i + 0] = n0 * inv;
    out_n[3 * i + 1] = n1 * inv;
    out_n[3 * i + 2] = n2 * inv;
}

extern "C" void kernel_launch(void* const* d_in, const int* in_sizes, int n_in,
                              void* d_out, int out_size, void* d_ws, size_t ws_size,
                              hipStream_t stream) {
    const float* coords = (const float*)d_in[0];
    const float* albedo = (const float*)d_in[1];
    const float* normal = (const float*)d_in[2];

    int M = in_sizes[0] / 3;
    long long normal_elems = (long long)in_sizes[2];
    long long n4 = normal_elems / 4;
    int tail_cnt = (int)(normal_elems & 3);
    const unsigned int* normal_tail = (const unsigned int*)normal + n4 * 4;

    float* out = (float*)d_out;
    float* out_a = out;
    float* out_n = out + M;

    // ws layout:
    //   [flag u32 @0][ovf_cnt u32 @64]
    //   [cnt u32[NCELL] @4096, 32 KiB]
    //   [recs float4[NCELL*CAP] @65536, 64 MiB]
    //   [ovf float4[M] after recs]
    size_t cnt_off = 4096;
    size_t rec_off = 65536;
    size_t rec_bytes = (size_t)NCELL * CAP * 16;
    size_t ovf_off = rec_off + rec_bytes;
    size_t ovf_bytes = (size_t)M * 16;
    if (ws_size < ovf_off + ovf_bytes) {
        int nblk = (M + 255) / 256;
        devox_direct<<<nblk, 256, 0, stream>>>(coords, albedo, normal, out_a, out_n, M);
        return;
    }

    unsigned int* flag = (unsigned int*)d_ws;
    unsigned int* ovf_cnt = (unsigned int*)((char*)d_ws + 64);
    unsigned int* cnt = (unsigned int*)((char*)d_ws + cnt_off);
    float4* recs = (float4*)((char*)d_ws + rec_off);
    float4* ovf = (float4*)((char*)d_ws + ovf_off);

    // zero flag + ovf_cnt + cnt
    (void)hipMemsetAsync(d_ws, 0, cnt_off + (size_t)NCELL * 4, stream);

    // kernel A: scatter (SB) + zcheck (ZB) + out_n fill (FB)
    int SB = (M + 2047) / 2048;
    if (SB < 1) SB = 1;
    int ZB = 3072;
    long long total_n = 3LL * M;
    int FB = ((M & 3) == 0) ? (int)((total_n / 4 + 255) / 256) : 2048;
    if (FB < 1) FB = 1;
    scatter_zcheck_fill_kernel<<<SB + ZB + FB, 256, 0, stream>>>(
        coords, (const u32x4*)normal, normal_tail, tail_cnt,
        flag, cnt, ovf_cnt, recs, ovf, out_n, M, n4, SB, ZB, FB);

    // kernel B: per-cell LDS-staged interp (exact fp32 taps)
    interp_cell_kernel<<<NCELL, 256, 0, stream>>>(albedo, cnt, recs, out_a);

    // kernel C: overflow cleanup (no-op when no cell exceeded CAP)
    overflow_kernel<<<256, 256, 0, stream>>>(ovf, ovf_cnt, albedo, out_a, M);

    // slow path (only does work when normal grid has nonzero content)
    normal_full_kernel<<<2048, 256, 0, stream>>>(coords, normal, flag, out_n, M);
}